// Round 14
// baseline (223.583 us; speedup 1.0000x reference)
//
#include <hip/hip_runtime.h>

typedef unsigned int uint;
typedef unsigned short u16;
using bf8    = __attribute__((ext_vector_type(8))) short;
using f32x4  = __attribute__((ext_vector_type(4))) float;
using f32x16 = __attribute__((ext_vector_type(16))) float;
using u16x4  = __attribute__((ext_vector_type(4))) unsigned short;

__device__ __forceinline__ u16 f2b(float f) {
    uint u = __builtin_bit_cast(uint, f);
    u += 0x7FFFu + ((u >> 16) & 1u);
    return (u16)(u >> 16);
}

#define CVTPK(lo, hi_) ({ uint r_; asm("v_cvt_pk_bf16_f32 %0, %1, %2" : "=v"(r_) : "v"(lo), "v"(hi_)); r_; })
#define SWAP32(a, b)   asm("v_permlane32_swap_b32 %0, %1" : "+v"(a), "+v"(b))

// Build PV B-fragment (16 kv rows x 32 q cols slice) from 8 f32 P values.
__device__ __forceinline__ bf8 mk_pb(float p0, float p1, float p2, float p3,
                                     float p4, float p5, float p6, float p7) {
    uint a0 = CVTPK(p0, p1), b0 = CVTPK(p4, p5);
    uint a1 = CVTPK(p2, p3), b1 = CVTPK(p6, p7);
    SWAP32(a0, b0);
    SWAP32(a1, b1);
    union { uint u[4]; bf8 v; } r;
    r.u[0] = a0; r.u[1] = a1; r.u[2] = b0; r.u[3] = b1;
    return r.v;
}

// ---- weight transpose + convert: W[k][n] f32 -> Wt[n][k] bf16 ----
__global__ __launch_bounds__(256) void k_wt(
    const float* __restrict__ w0, const float* __restrict__ w1,
    const float* __restrict__ w2, const float* __restrict__ w3,
    u16* __restrict__ o0, u16* __restrict__ o1,
    u16* __restrict__ o2, u16* __restrict__ o3)
{
    const float* w; u16* o;
    switch (blockIdx.z) {
        case 0: w = w0; o = o0; break;
        case 1: w = w1; o = o1; break;
        case 2: w = w2; o = o2; break;
        default: w = w3; o = o3; break;
    }
    __shared__ float t[32][33];
    int n0 = blockIdx.x * 32, k0 = blockIdx.y * 32;
    int tr = threadIdx.x >> 5, tc = threadIdx.x & 31;
    for (int i = 0; i < 4; ++i) {
        int r = i * 8 + tr;
        t[r][tc] = w[(size_t)(k0 + r) * 1024 + n0 + tc];
    }
    __syncthreads();
    for (int i = 0; i < 4; ++i) {
        int r = i * 8 + tr;
        o[(size_t)(n0 + r) * 1024 + k0 + tc] = f2b(t[tc][r]);
    }
}

// ---- fp32 -> bf16 convert for activations (Q,K,V) ----
__global__ __launch_bounds__(256) void k_cvt(
    const float* __restrict__ s0, const float* __restrict__ s1, const float* __restrict__ s2,
    u16* __restrict__ d0, u16* __restrict__ d1, u16* __restrict__ d2)
{
    const float* s; u16* d;
    switch (blockIdx.z) {
        case 0: s = s0; d = d0; break;
        case 1: s = s1; d = d1; break;
        default: s = s2; d = d2; break;
    }
    size_t i = ((size_t)blockIdx.x * 256 + threadIdx.x) * 8;
    float4 a = *(const float4*)(s + i);
    float4 b = *(const float4*)(s + i + 4);
    uint4 o;
    o.x = CVTPK(a.x, a.y);
    o.y = CVTPK(a.z, a.w);
    o.z = CVTPK(b.x, b.y);
    o.w = CVTPK(b.z, b.w);
    *(uint4*)(d + i) = o;
}

// ---- GEMM body: 128x128 tile, BK=64, 72-pad LDS, reg-staged + T14 split ----
// Tile t+1's global loads are issued DURING compute(t) (into registers);
// the LDS write happens after the next barrier. Same 2 barriers per step.
#define GEMM_BODY(A_, Bt_)                                                                   \
    __shared__ u16 lA[128 * 72];                                                             \
    __shared__ u16 lB[128 * 72];                                                             \
    int tid = threadIdx.x;                                                                   \
    int lane = tid & 63, wid = tid >> 6;                                                     \
    int wm = wid >> 1, wn = wid & 1;                                                         \
    int m0 = blockIdx.x * 128, n0 = blockIdx.y * 128;                                        \
    int lr = lane & 15, lg = lane >> 4;                                                      \
    int sr_ = tid >> 3, sc_ = (tid & 7) * 8;                                                 \
    f32x4 acc[4][4] = {};                                                                    \
    uint4 pa[4], pb[4];                                                                      \
    _Pragma("unroll")                                                                        \
    for (int i = 0; i < 4; ++i) {                                                            \
        int r = i * 32 + sr_;                                                                \
        pa[i] = *(const uint4*)&A_[(size_t)(m0 + r) * 1024 + sc_];                           \
        pb[i] = *(const uint4*)&Bt_[(size_t)(n0 + r) * 1024 + sc_];                          \
    }                                                                                        \
    for (int t = 0; t < 16; ++t) {                                                           \
        __syncthreads();                                                                     \
        _Pragma("unroll")                                                                    \
        for (int i = 0; i < 4; ++i) {                                                        \
            int r = i * 32 + sr_;                                                            \
            *(uint4*)&lA[r * 72 + sc_] = pa[i];                                              \
            *(uint4*)&lB[r * 72 + sc_] = pb[i];                                              \
        }                                                                                    \
        if (t < 15) {                                                                        \
            int k1 = (t + 1) * 64;                                                           \
            _Pragma("unroll")                                                                \
            for (int i = 0; i < 4; ++i) {                                                    \
                int r = i * 32 + sr_;                                                        \
                pa[i] = *(const uint4*)&A_[(size_t)(m0 + r) * 1024 + k1 + sc_];              \
                pb[i] = *(const uint4*)&Bt_[(size_t)(n0 + r) * 1024 + k1 + sc_];             \
            }                                                                                \
        }                                                                                    \
        __syncthreads();                                                                     \
        _Pragma("unroll")                                                                    \
        for (int kk = 0; kk < 64; kk += 32) {                                                \
            bf8 af[4], bfr[4];                                                               \
            int ko = kk + lg * 8;                                                            \
            _Pragma("unroll")                                                                \
            for (int m = 0; m < 4; ++m) af[m]  = *(const bf8*)&lA[(wm * 64 + m * 16 + lr) * 72 + ko]; \
            _Pragma("unroll")                                                                \
            for (int n = 0; n < 4; ++n) bfr[n] = *(const bf8*)&lB[(wn * 64 + n * 16 + lr) * 72 + ko]; \
            _Pragma("unroll")                                                                \
            for (int m = 0; m < 4; ++m)                                                      \
                _Pragma("unroll")                                                            \
                for (int n = 0; n < 4; ++n)                                                  \
                    acc[m][n] = __builtin_amdgcn_mfma_f32_16x16x32_bf16(af[m], bfr[n], acc[m][n], 0, 0, 0); \
        }                                                                                    \
    }

// ---- merged Q/K/V projection GEMM (bf16 A) ----
// epi 0: natural bf16 out[R][C] = (acc+b)*scale   (q, k)
// epi 1: transposed bf16 vth[bh][dh][s]           (v)
__global__ __launch_bounds__(256) void k_gemm_qkv(
    const u16* __restrict__ Xq, const u16* __restrict__ Xk, const u16* __restrict__ Xv,
    const u16* __restrict__ WtQ, const u16* __restrict__ WtK, const u16* __restrict__ WtV,
    const float* __restrict__ bQ, const float* __restrict__ bK, const float* __restrict__ bV,
    u16* __restrict__ qn, u16* __restrict__ kn, u16* __restrict__ vth, float qscale)
{
    const u16 *A, *Bt; const float* bias; u16* outp; int epi; float scale;
    switch (blockIdx.z) {
        case 0:  A = Xq; Bt = WtQ; bias = bQ; outp = qn;  epi = 0; scale = qscale; break;
        case 1:  A = Xk; Bt = WtK; bias = bK; outp = kn;  epi = 0; scale = 1.0f;   break;
        default: A = Xv; Bt = WtV; bias = bV; outp = vth; epi = 1; scale = 1.0f;   break;
    }
    GEMM_BODY(A, Bt)
    for (int m = 0; m < 4; ++m) {
        int Rb = m0 + wm * 64 + m * 16 + lg * 4;
        for (int n = 0; n < 4; ++n) {
            int C = n0 + wn * 64 + n * 16 + lr;
            float bv = bias[C];
            if (epi == 0) {
                for (int r = 0; r < 4; ++r)
                    outp[(size_t)(Rb + r) * 1024 + C] = f2b((acc[m][n][r] + bv) * scale);
            } else {
                int h = C >> 6, dh = C & 63;
                int b = Rb >> 11, s = Rb & 2047;
                u16x4 pk;
                for (int r = 0; r < 4; ++r) pk[r] = f2b(acc[m][n][r] + bv);
                *(u16x4*)&vth[((size_t)(b * 16 + h) * 64 + dh) * 2048 + s] = pk;
            }
        }
    }
}

// ---- output GEMM: ctx(bf16) @ WO + bO, * mask -> fp32 ----
__global__ __launch_bounds__(256) void k_gemm_out(
    const u16* __restrict__ Actx, const u16* __restrict__ WtO,
    const float* __restrict__ bias, const float* __restrict__ mask,
    float* __restrict__ outp)
{
    GEMM_BODY(Actx, WtO)
    for (int m = 0; m < 4; ++m) {
        int Rb = m0 + wm * 64 + m * 16 + lg * 4;
        for (int n = 0; n < 4; ++n) {
            int C = n0 + wn * 64 + n * 16 + lr;
            float bv = bias[C];
            for (int r = 0; r < 4; ++r) {
                int R = Rb + r;
                outp[(size_t)R * 1024 + C] = (acc[m][n][r] + bv) * mask[R];
            }
        }
    }
}

// ---- flash attention, 32x32 swapped operands, no-max-tracking softmax ----
// Single-buffer LDS, two __syncthreads per KV tile — EXACT R11 structure
// (passed 4x at absmax 5.04e-4). XCD-swizzle and setprio retired: both
// session failures (R9 2.7e-3, R12 1.7e-2) contained exactly that pair.
__global__ __launch_bounds__(256) void k_flash(
    const u16* __restrict__ qn, const u16* __restrict__ kn,
    const u16* __restrict__ vt, u16* __restrict__ ctx)
{
    __shared__ char lK[8192];   // K tile [kv64][d64], byte ^= (kv&7)<<4
    __shared__ char lV[8192];   // Vt tile [d64][kv64], byte ^= (d&7)<<4
    const int S = 2048;
    int bh = blockIdx.y;
    int b = bh >> 4, h = bh & 15;
    int q0 = blockIdx.x * 128;
    int tid = threadIdx.x, lane = tid & 63, w = tid >> 6;
    int l31 = lane & 31, hi = lane >> 5;

    int qrow = q0 + w * 32 + l31;
    bf8 qf[4];
    const u16* qbase = &qn[((size_t)(b * 2048 + qrow)) * 1024 + h * 64 + hi * 8];
#pragma unroll
    for (int dk = 0; dk < 4; ++dk) qf[dk] = *(const bf8*)&qbase[dk * 16];

    bf8 ones;
#pragma unroll
    for (int i = 0; i < 8; ++i) ones[i] = (short)0x3F80;   // bf16 1.0

    f32x16 o0 = {}, o1 = {}, o2 = {};   // O rows 0..31 / 32..63; o2 = P row-sum

    int sr = tid >> 2;              // row 0..63
    int sc = (tid & 3) * 32;        // byte col {0,32,64,96}
    const u16* gK = &kn[((size_t)(b * 2048 + sr)) * 1024 + h * 64 + (sc >> 1)];
    const u16* gV = &vt[((size_t)bh * 64 + sr) * 2048 + (sc >> 1)];
    int wA0 = sr * 128 + (sc        ^ ((sr & 7) << 4));
    int wA1 = sr * 128 + ((sc + 16) ^ ((sr & 7) << 4));

    uint4 ra0 = *(const uint4*)(gK);
    uint4 ra1 = *(const uint4*)(gK + 8);
    uint4 rb0 = *(const uint4*)(gV);
    uint4 rb1 = *(const uint4*)(gV + 8);

    int swzK = ((l31 & 7) << 4);
    for (int k0 = 0; k0 < S; k0 += 64) {
        __syncthreads();
        *(uint4*)&lK[wA0] = ra0; *(uint4*)&lK[wA1] = ra1;
        *(uint4*)&lV[wA0] = rb0; *(uint4*)&lV[wA1] = rb1;
        if (k0 + 64 < S) {      // T14: issue next tile's loads before compute
            ra0 = *(const uint4*)(gK + (size_t)(k0 + 64) * 1024);
            ra1 = *(const uint4*)(gK + (size_t)(k0 + 64) * 1024 + 8);
            rb0 = *(const uint4*)(gV + k0 + 64);
            rb1 = *(const uint4*)(gV + k0 + 64 + 8);
        }
        __syncthreads();

        f32x16 s0 = {}, s1 = {};
#pragma unroll
        for (int dk = 0; dk < 4; ++dk) {
            int cb = dk * 32 + hi * 16;
            bf8 kf0 = *(const bf8*)&lK[l31 * 128 + (cb ^ swzK)];
            bf8 kf1 = *(const bf8*)&lK[(32 + l31) * 128 + (cb ^ swzK)];
            s0 = __builtin_amdgcn_mfma_f32_32x32x16_bf16(kf0, qf[dk], s0, 0, 0, 0);
            s1 = __builtin_amdgcn_mfma_f32_32x32x16_bf16(kf1, qf[dk], s1, 0, 0, 0);
        }

#pragma unroll
        for (int i = 0; i < 16; ++i) s0[i] = __builtin_amdgcn_exp2f(s0[i]);
#pragma unroll
        for (int i = 0; i < 16; ++i) s1[i] = __builtin_amdgcn_exp2f(s1[i]);

        bf8 pb0 = mk_pb(s0[0], s0[1], s0[2],  s0[3],  s0[4],  s0[5],  s0[6],  s0[7]);
        bf8 pb1 = mk_pb(s0[8], s0[9], s0[10], s0[11], s0[12], s0[13], s0[14], s0[15]);
        bf8 pb2 = mk_pb(s1[0], s1[1], s1[2],  s1[3],  s1[4],  s1[5],  s1[6],  s1[7]);
        bf8 pb3 = mk_pb(s1[8], s1[9], s1[10], s1[11], s1[12], s1[13], s1[14], s1[15]);

#pragma unroll
        for (int ks = 0; ks < 4; ++ks) {
            bf8 pb = (ks == 0) ? pb0 : (ks == 1) ? pb1 : (ks == 2) ? pb2 : pb3;
            int cb = ks * 32 + hi * 16;
            bf8 vf0 = *(const bf8*)&lV[l31 * 128 + (cb ^ swzK)];
            bf8 vf1 = *(const bf8*)&lV[(32 + l31) * 128 + (cb ^ swzK)];
            o0 = __builtin_amdgcn_mfma_f32_32x32x16_bf16(vf0, pb, o0, 0, 0, 0);
            o1 = __builtin_amdgcn_mfma_f32_32x32x16_bf16(vf1, pb, o1, 0, 0, 0);
            o2 = __builtin_amdgcn_mfma_f32_32x32x16_bf16(ones, pb, o2, 0, 0, 0);
        }
    }

    float rinv = 1.f / o2[0];
    size_t obase = ((size_t)(b * 2048 + qrow)) * 1024 + h * 64;
#pragma unroll
    for (int k = 0; k < 4; ++k) {
        u16x4 v0, v1;
#pragma unroll
        for (int j = 0; j < 4; ++j) {
            v0[j] = f2b(o0[k * 4 + j] * rinv);
            v1[j] = f2b(o1[k * 4 + j] * rinv);
        }
        *(u16x4*)&ctx[obase + 8 * k + 4 * hi]      = v0;
        *(u16x4*)&ctx[obase + 32 + 8 * k + 4 * hi] = v1;
    }
}

extern "C" void kernel_launch(void* const* d_in, const int* in_sizes, int n_in,
                              void* d_out, int out_size, void* d_ws, size_t ws_size,
                              hipStream_t stream)
{
    const float* V    = (const float*)d_in[0];
    const float* Q    = (const float*)d_in[1];
    const float* Kin  = (const float*)d_in[2];
    const float* mask = (const float*)d_in[3];
    const float* WQ   = (const float*)d_in[4];
    const float* bQ   = (const float*)d_in[5];
    const float* WK   = (const float*)d_in[6];
    const float* bK   = (const float*)d_in[7];
    const float* WV   = (const float*)d_in[8];
    const float* bV   = (const float*)d_in[9];
    const float* WO   = (const float*)d_in[10];
    const float* bO   = (const float*)d_in[11];
    float* out = (float*)d_out;

    u16* base = (u16*)d_ws;
    const size_t NE = (size_t)4096 * 1024;
    const size_t NW = (size_t)1024 * 1024;
    u16* Xq  = base;            // bf16 activations
    u16* Xk  = Xq + NE;
    u16* Xv  = Xk + NE;
    u16* qn  = Xv + NE;         // q heads, natural [B*S][1024] bf16
    u16* kn  = qn + NE;         // k heads, natural
    u16* vth = kn + NE;         // v heads  [B,H,64,S]
    u16* ctx = vth + NE;        // ctx      [B*S][1024]
    u16* WtQ = ctx + NE;
    u16* WtK = WtQ + NW;
    u16* WtV = WtK + NW;
    u16* WtO = WtV + NW;

    // q scale folds 1/sqrt(1024) and log2(e) so flash softmax can use exp2
    const float qscale = 0.03125f * 1.44269504f;

    k_wt <<<dim3(32, 32, 4), 256, 0, stream>>>(WQ, WK, WV, WO, WtQ, WtK, WtV, WtO);
    k_cvt<<<dim3(2048, 1, 3), 256, 0, stream>>>(Q, Kin, V, Xq, Xk, Xv);
    k_gemm_qkv<<<dim3(32, 8, 3), 256, 0, stream>>>(Xq, Xk, Xv, WtQ, WtK, WtV,
                                                   bQ, bK, bV, qn, kn, vth, qscale);
    k_flash<<<dim3(16, 32), 256, 0, stream>>>(qn, kn, vth, ctx);
    k_gemm_out<<<dim3(32, 8), 256, 0, stream>>>(ctx, WtO, bO, mask, out);
}

// Round 15
// 133.076 us; speedup vs baseline: 1.6801x; 1.6801x over previous
//
#include <hip/hip_runtime.h>

typedef unsigned int uint;
typedef unsigned short u16;
using bf8    = __attribute__((ext_vector_type(8))) short;
using f32x4  = __attribute__((ext_vector_type(4))) float;
using f32x16 = __attribute__((ext_vector_type(16))) float;
using u16x4  = __attribute__((ext_vector_type(4))) unsigned short;

__device__ __forceinline__ u16 f2b(float f) {
    uint u = __builtin_bit_cast(uint, f);
    u += 0x7FFFu + ((u >> 16) & 1u);
    return (u16)(u >> 16);
}

#define CVTPK(lo, hi_) ({ uint r_; asm("v_cvt_pk_bf16_f32 %0, %1, %2" : "=v"(r_) : "v"(lo), "v"(hi_)); r_; })
#define SWAP32(a, b)   asm("v_permlane32_swap_b32 %0, %1" : "+v"(a), "+v"(b))

// Build PV B-fragment (16 kv rows x 32 q cols slice) from 8 f32 P values.
__device__ __forceinline__ bf8 mk_pb(float p0, float p1, float p2, float p3,
                                     float p4, float p5, float p6, float p7) {
    uint a0 = CVTPK(p0, p1), b0 = CVTPK(p4, p5);
    uint a1 = CVTPK(p2, p3), b1 = CVTPK(p6, p7);
    SWAP32(a0, b0);
    SWAP32(a1, b1);
    union { uint u[4]; bf8 v; } r;
    r.u[0] = a0; r.u[1] = a1; r.u[2] = b0; r.u[3] = b1;
    return r.v;
}

// ---- merged prep: weight transpose+convert AND activation convert, 1 launch ----
// blocks [0,4096): W[k][n] f32 -> Wt[n][k] bf16 (4 weights x 1024 32x32 tiles)
// blocks [4096,10240): Q/K/V f32 -> bf16 (3 tensors x 2048 chunks)
__global__ __launch_bounds__(256) void k_prep(
    const float* __restrict__ w0, const float* __restrict__ w1,
    const float* __restrict__ w2, const float* __restrict__ w3,
    u16* __restrict__ o0, u16* __restrict__ o1,
    u16* __restrict__ o2, u16* __restrict__ o3,
    const float* __restrict__ s0, const float* __restrict__ s1, const float* __restrict__ s2,
    u16* __restrict__ d0, u16* __restrict__ d1, u16* __restrict__ d2)
{
    __shared__ float t[32][33];
    int blk = blockIdx.x;
    if (blk < 4096) {
        const float* w; u16* o;
        switch (blk >> 10) {
            case 0: w = w0; o = o0; break;
            case 1: w = w1; o = o1; break;
            case 2: w = w2; o = o2; break;
            default: w = w3; o = o3; break;
        }
        int tl = blk & 1023;
        int n0 = (tl & 31) * 32, k0 = (tl >> 5) * 32;
        int tr = threadIdx.x >> 5, tc = threadIdx.x & 31;
        for (int i = 0; i < 4; ++i) {
            int r = i * 8 + tr;
            t[r][tc] = w[(size_t)(k0 + r) * 1024 + n0 + tc];
        }
        __syncthreads();
        for (int i = 0; i < 4; ++i) {
            int r = i * 8 + tr;
            o[(size_t)(n0 + r) * 1024 + k0 + tc] = f2b(t[tc][r]);
        }
    } else {
        int c = blk - 4096;
        const float* s; u16* d;
        switch (c >> 11) {
            case 0: s = s0; d = d0; break;
            case 1: s = s1; d = d1; break;
            default: s = s2; d = d2; break;
        }
        size_t i = ((size_t)(c & 2047) * 256 + threadIdx.x) * 8;
        float4 a = *(const float4*)(s + i);
        float4 b = *(const float4*)(s + i + 4);
        uint4 o;
        o.x = CVTPK(a.x, a.y);
        o.y = CVTPK(a.z, a.w);
        o.z = CVTPK(b.x, b.y);
        o.w = CVTPK(b.z, b.w);
        *(uint4*)(d + i) = o;
    }
}

// ---- GEMM body: 128x128 tile, BK=64, 72-pad LDS, reg-staged (R5 structure,
// best measured: qkv ~44us vs gload16 59.6 / dbuf 65 / fused-cvt 74 / T14 124) ----
#define GEMM_BODY(A_, Bt_)                                                                   \
    __shared__ u16 lA[128 * 72];                                                             \
    __shared__ u16 lB[128 * 72];                                                             \
    int tid = threadIdx.x;                                                                   \
    int lane = tid & 63, wid = tid >> 6;                                                     \
    int wm = wid >> 1, wn = wid & 1;                                                         \
    int m0 = blockIdx.x * 128, n0 = blockIdx.y * 128;                                        \
    int lr = lane & 15, lg = lane >> 4;                                                      \
    f32x4 acc[4][4] = {};                                                                    \
    for (int k0 = 0; k0 < 1024; k0 += 64) {                                                  \
        __syncthreads();                                                                     \
        _Pragma("unroll")                                                                    \
        for (int i = 0; i < 4; ++i) {                                                        \
            int c = i * 256 + tid;                                                           \
            int r = c >> 3, c8 = (c & 7) * 8;                                                \
            *(uint4*)&lA[r * 72 + c8] = *(const uint4*)&A_[(size_t)(m0 + r) * 1024 + k0 + c8];  \
            *(uint4*)&lB[r * 72 + c8] = *(const uint4*)&Bt_[(size_t)(n0 + r) * 1024 + k0 + c8]; \
        }                                                                                    \
        __syncthreads();                                                                     \
        _Pragma("unroll")                                                                    \
        for (int kk = 0; kk < 64; kk += 32) {                                                \
            bf8 af[4], bfr[4];                                                               \
            int ko = kk + lg * 8;                                                            \
            _Pragma("unroll")                                                                \
            for (int m = 0; m < 4; ++m) af[m]  = *(const bf8*)&lA[(wm * 64 + m * 16 + lr) * 72 + ko]; \
            _Pragma("unroll")                                                                \
            for (int n = 0; n < 4; ++n) bfr[n] = *(const bf8*)&lB[(wn * 64 + n * 16 + lr) * 72 + ko]; \
            _Pragma("unroll")                                                                \
            for (int m = 0; m < 4; ++m)                                                      \
                _Pragma("unroll")                                                            \
                for (int n = 0; n < 4; ++n)                                                  \
                    acc[m][n] = __builtin_amdgcn_mfma_f32_16x16x32_bf16(af[m], bfr[n], acc[m][n], 0, 0, 0); \
        }                                                                                    \
    }

// ---- merged Q/K/V projection GEMM (bf16 A) ----
// epi 0: natural bf16 out[R][C] = (acc+b)*scale   (q, k)
// epi 1: transposed bf16 vth[bh][dh][s]           (v)
__global__ __launch_bounds__(256) void k_gemm_qkv(
    const u16* __restrict__ Xq, const u16* __restrict__ Xk, const u16* __restrict__ Xv,
    const u16* __restrict__ WtQ, const u16* __restrict__ WtK, const u16* __restrict__ WtV,
    const float* __restrict__ bQ, const float* __restrict__ bK, const float* __restrict__ bV,
    u16* __restrict__ qn, u16* __restrict__ kn, u16* __restrict__ vth, float qscale)
{
    const u16 *A, *Bt; const float* bias; u16* outp; int epi; float scale;
    switch (blockIdx.z) {
        case 0:  A = Xq; Bt = WtQ; bias = bQ; outp = qn;  epi = 0; scale = qscale; break;
        case 1:  A = Xk; Bt = WtK; bias = bK; outp = kn;  epi = 0; scale = 1.0f;   break;
        default: A = Xv; Bt = WtV; bias = bV; outp = vth; epi = 1; scale = 1.0f;   break;
    }
    GEMM_BODY(A, Bt)
    for (int m = 0; m < 4; ++m) {
        int Rb = m0 + wm * 64 + m * 16 + lg * 4;
        for (int n = 0; n < 4; ++n) {
            int C = n0 + wn * 64 + n * 16 + lr;
            float bv = bias[C];
            if (epi == 0) {
                for (int r = 0; r < 4; ++r)
                    outp[(size_t)(Rb + r) * 1024 + C] = f2b((acc[m][n][r] + bv) * scale);
            } else {
                int h = C >> 6, dh = C & 63;
                int b = Rb >> 11, s = Rb & 2047;
                u16x4 pk;
                for (int r = 0; r < 4; ++r) pk[r] = f2b(acc[m][n][r] + bv);
                *(u16x4*)&vth[((size_t)(b * 16 + h) * 64 + dh) * 2048 + s] = pk;
            }
        }
    }
}

// ---- output GEMM: ctx(bf16) @ WO + bO, * mask -> fp32 ----
__global__ __launch_bounds__(256) void k_gemm_out(
    const u16* __restrict__ Actx, const u16* __restrict__ WtO,
    const float* __restrict__ bias, const float* __restrict__ mask,
    float* __restrict__ outp)
{
    GEMM_BODY(Actx, WtO)
    for (int m = 0; m < 4; ++m) {
        int Rb = m0 + wm * 64 + m * 16 + lg * 4;
        for (int n = 0; n < 4; ++n) {
            int C = n0 + wn * 64 + n * 16 + lr;
            float bv = bias[C];
            for (int r = 0; r < 4; ++r) {
                int R = Rb + r;
                outp[(size_t)R * 1024 + C] = (acc[m][n][r] + bv) * mask[R];
            }
        }
    }
}

// ---- flash attention, 32x32 swapped operands, no-max-tracking softmax ----
// Single-buffer LDS, two __syncthreads per KV tile — EXACT R11 structure
// (passed 5x at absmax 5.04e-4). XCD-swizzle and setprio retired: both
// session failures (R9 2.7e-3, R12 1.7e-2) contained exactly that pair.
__global__ __launch_bounds__(256) void k_flash(
    const u16* __restrict__ qn, const u16* __restrict__ kn,
    const u16* __restrict__ vt, u16* __restrict__ ctx)
{
    __shared__ char lK[8192];   // K tile [kv64][d64], byte ^= (kv&7)<<4
    __shared__ char lV[8192];   // Vt tile [d64][kv64], byte ^= (d&7)<<4
    const int S = 2048;
    int bh = blockIdx.y;
    int b = bh >> 4, h = bh & 15;
    int q0 = blockIdx.x * 128;
    int tid = threadIdx.x, lane = tid & 63, w = tid >> 6;
    int l31 = lane & 31, hi = lane >> 5;

    int qrow = q0 + w * 32 + l31;
    bf8 qf[4];
    const u16* qbase = &qn[((size_t)(b * 2048 + qrow)) * 1024 + h * 64 + hi * 8];
#pragma unroll
    for (int dk = 0; dk < 4; ++dk) qf[dk] = *(const bf8*)&qbase[dk * 16];

    bf8 ones;
#pragma unroll
    for (int i = 0; i < 8; ++i) ones[i] = (short)0x3F80;   // bf16 1.0

    f32x16 o0 = {}, o1 = {}, o2 = {};   // O rows 0..31 / 32..63; o2 = P row-sum

    int sr = tid >> 2;              // row 0..63
    int sc = (tid & 3) * 32;        // byte col {0,32,64,96}
    const u16* gK = &kn[((size_t)(b * 2048 + sr)) * 1024 + h * 64 + (sc >> 1)];
    const u16* gV = &vt[((size_t)bh * 64 + sr) * 2048 + (sc >> 1)];
    int wA0 = sr * 128 + (sc        ^ ((sr & 7) << 4));
    int wA1 = sr * 128 + ((sc + 16) ^ ((sr & 7) << 4));

    uint4 ra0 = *(const uint4*)(gK);
    uint4 ra1 = *(const uint4*)(gK + 8);
    uint4 rb0 = *(const uint4*)(gV);
    uint4 rb1 = *(const uint4*)(gV + 8);

    int swzK = ((l31 & 7) << 4);
    for (int k0 = 0; k0 < S; k0 += 64) {
        __syncthreads();
        *(uint4*)&lK[wA0] = ra0; *(uint4*)&lK[wA1] = ra1;
        *(uint4*)&lV[wA0] = rb0; *(uint4*)&lV[wA1] = rb1;
        if (k0 + 64 < S) {      // issue next tile's loads before compute
            ra0 = *(const uint4*)(gK + (size_t)(k0 + 64) * 1024);
            ra1 = *(const uint4*)(gK + (size_t)(k0 + 64) * 1024 + 8);
            rb0 = *(const uint4*)(gV + k0 + 64);
            rb1 = *(const uint4*)(gV + k0 + 64 + 8);
        }
        __syncthreads();

        f32x16 s0 = {}, s1 = {};
#pragma unroll
        for (int dk = 0; dk < 4; ++dk) {
            int cb = dk * 32 + hi * 16;
            bf8 kf0 = *(const bf8*)&lK[l31 * 128 + (cb ^ swzK)];
            bf8 kf1 = *(const bf8*)&lK[(32 + l31) * 128 + (cb ^ swzK)];
            s0 = __builtin_amdgcn_mfma_f32_32x32x16_bf16(kf0, qf[dk], s0, 0, 0, 0);
            s1 = __builtin_amdgcn_mfma_f32_32x32x16_bf16(kf1, qf[dk], s1, 0, 0, 0);
        }

#pragma unroll
        for (int i = 0; i < 16; ++i) s0[i] = __builtin_amdgcn_exp2f(s0[i]);
#pragma unroll
        for (int i = 0; i < 16; ++i) s1[i] = __builtin_amdgcn_exp2f(s1[i]);

        bf8 pb0 = mk_pb(s0[0], s0[1], s0[2],  s0[3],  s0[4],  s0[5],  s0[6],  s0[7]);
        bf8 pb1 = mk_pb(s0[8], s0[9], s0[10], s0[11], s0[12], s0[13], s0[14], s0[15]);
        bf8 pb2 = mk_pb(s1[0], s1[1], s1[2],  s1[3],  s1[4],  s1[5],  s1[6],  s1[7]);
        bf8 pb3 = mk_pb(s1[8], s1[9], s1[10], s1[11], s1[12], s1[13], s1[14], s1[15]);

#pragma unroll
        for (int ks = 0; ks < 4; ++ks) {
            bf8 pb = (ks == 0) ? pb0 : (ks == 1) ? pb1 : (ks == 2) ? pb2 : pb3;
            int cb = ks * 32 + hi * 16;
            bf8 vf0 = *(const bf8*)&lV[l31 * 128 + (cb ^ swzK)];
            bf8 vf1 = *(const bf8*)&lV[(32 + l31) * 128 + (cb ^ swzK)];
            o0 = __builtin_amdgcn_mfma_f32_32x32x16_bf16(vf0, pb, o0, 0, 0, 0);
            o1 = __builtin_amdgcn_mfma_f32_32x32x16_bf16(vf1, pb, o1, 0, 0, 0);
            o2 = __builtin_amdgcn_mfma_f32_32x32x16_bf16(ones, pb, o2, 0, 0, 0);
        }
    }

    float rinv = 1.f / o2[0];
    size_t obase = ((size_t)(b * 2048 + qrow)) * 1024 + h * 64;
#pragma unroll
    for (int k = 0; k < 4; ++k) {
        u16x4 v0, v1;
#pragma unroll
        for (int j = 0; j < 4; ++j) {
            v0[j] = f2b(o0[k * 4 + j] * rinv);
            v1[j] = f2b(o1[k * 4 + j] * rinv);
        }
        *(u16x4*)&ctx[obase + 8 * k + 4 * hi]      = v0;
        *(u16x4*)&ctx[obase + 32 + 8 * k + 4 * hi] = v1;
    }
}

extern "C" void kernel_launch(void* const* d_in, const int* in_sizes, int n_in,
                              void* d_out, int out_size, void* d_ws, size_t ws_size,
                              hipStream_t stream)
{
    const float* V    = (const float*)d_in[0];
    const float* Q    = (const float*)d_in[1];
    const float* Kin  = (const float*)d_in[2];
    const float* mask = (const float*)d_in[3];
    const float* WQ   = (const float*)d_in[4];
    const float* bQ   = (const float*)d_in[5];
    const float* WK   = (const float*)d_in[6];
    const float* bK   = (const float*)d_in[7];
    const float* WV   = (const float*)d_in[8];
    const float* bV   = (const float*)d_in[9];
    const float* WO   = (const float*)d_in[10];
    const float* bO   = (const float*)d_in[11];
    float* out = (float*)d_out;

    u16* base = (u16*)d_ws;
    const size_t NE = (size_t)4096 * 1024;
    const size_t NW = (size_t)1024 * 1024;
    u16* Xq  = base;            // bf16 activations
    u16* Xk  = Xq + NE;
    u16* Xv  = Xk + NE;
    u16* qn  = Xv + NE;         // q heads, natural [B*S][1024] bf16
    u16* kn  = qn + NE;         // k heads, natural
    u16* vth = kn + NE;         // v heads  [B,H,64,S]
    u16* ctx = vth + NE;        // ctx      [B*S][1024]
    u16* WtQ = ctx + NE;
    u16* WtK = WtQ + NW;
    u16* WtV = WtK + NW;
    u16* WtO = WtV + NW;

    // q scale folds 1/sqrt(1024) and log2(e) so flash softmax can use exp2
    const float qscale = 0.03125f * 1.44269504f;

    k_prep<<<dim3(10240), 256, 0, stream>>>(WQ, WK, WV, WO, WtQ, WtK, WtV, WtO,
                                            Q, Kin, V, Xq, Xk, Xv);
    k_gemm_qkv<<<dim3(32, 8, 3), 256, 0, stream>>>(Xq, Xk, Xv, WtQ, WtK, WtV,
                                                   bQ, bK, bV, qn, kn, vth, qscale);
    k_flash<<<dim3(16, 32), 256, 0, stream>>>(qn, kn, vth, ctx);
    k_gemm_out<<<dim3(32, 8), 256, 0, stream>>>(ctx, WtO, bO, mask, out);
}